// Round 1
// baseline (207.902 us; speedup 1.0000x reference)
//
#include <hip/hip_runtime.h>
#include <math.h>

// Problem constants
#define NPIX    65536      // 256*256 pixels per camera
#define NBINS   64
#define NBATCH  32         // B*C = 4*8
#define SPLIT   32         // pixel-chunks per batch
#define BLOCKT  256        // 4 waves/block (R7: was 128)
#define PXPT    4          // pixels per thread per iteration
#define ITERS   (NPIX / SPLIT / (BLOCKT * PXPT))   // = 2 -> 8 px/thread
#define WIN     12         // centered window [j0-5, j0+6]: coverage >= +/-5 both
                           // sides (old 4-aligned scheme worst case was +3/-4)
#define NHIST   (BLOCKT / 16)       // 16 lanes share one histogram via ds_add_f32
#define HSTRIDE 72                  // dwords; 72 % 32 == 8 -> quarter-wave bank stagger
#define LDSN    (NHIST * HSTRIDE)   // 1152 floats = 4.6 KB (was 34.8 KB)
//
// R7 THEORY: old kernel was latency-bound on the per-pixel LDS b128 RMW chain
// (read->wait lgkmcnt->add->write, 16 round-trips/thread) at only 2 waves/SIMD
// (LDS-capped occupancy). Switch to fire-and-forget ds_add_f32 atomics into
// per-quarter-wave histograms: zero lgkmcnt waits in the main loop, LDS 34.8KB
// -> 4.6KB, occupancy 8 -> 16 waves/CU. W[4][12] staging array eliminated
// (weights consumed immediately) -> ~48 fewer VGPRs.
// NOTE (R6, still applies): 2-deep software prefetch of global loads REGRESSED;
// keep simple per-iteration loads.

#define THREE_LOG2E 4.328085122666891f

__global__ __launch_bounds__(BLOCKT, 4) void spad_hist_kernel(
    const float* __restrict__ normals,      // [32, 65536, 3]
    const float* __restrict__ inters,       // [32, 65536, 3]
    const float* __restrict__ film,         // [65536, 3]
    const float* __restrict__ cosm,         // [65536]
    float* __restrict__ ws,                 // [1024, 64] block partials
    float kconst, float lmask_c, float half_inv_bin)
{
    __shared__ float hist[LDSN];
    const int tid = threadIdx.x;
    for (int i = tid; i < LDSN; i += BLOCKT) hist[i] = 0.0f;
    __syncthreads();

    const int b = blockIdx.x & (NBATCH - 1);
    const int chunk = blockIdx.x / NBATCH;
    const int pix0 = chunk * (NPIX / SPLIT);
    // quarter-wave histogram base: lanes 16q..16q+15 share one histogram;
    // bases are 8 banks apart within a wave's 4 groups (72 % 32 == 8)
    float* const hq = &hist[(tid >> 4) * HSTRIDE];

    // E3^m, m=0..12 — independent scaling breaks the serial exp chain
    const float E3P[13] = {
        1.0f, 20.085536923187668f, 403.4287934927351f, 8103.083927575384f,
        162754.79141900392f, 3269017.372472111f, 65659969.13733051f,
        1318815734.4832146f, 26489122129.843472f, 532048240601.79865f,
        10686474581524.462f, 214643579785916.06f, 4311231547115195.0f };

    #pragma unroll
    for (int it = 0; it < ITERS; ++it) {
        const int pp = pix0 + (it * BLOCKT + tid) * PXPT;
        const float4* n4 = (const float4*)(normals + ((size_t)b * NPIX + pp) * 3);
        const float4* i4 = (const float4*)(inters  + ((size_t)b * NPIX + pp) * 3);
        const float4* f4 = (const float4*)(film + (size_t)pp * 3);
        const float4  c4 = *(const float4*)(cosm + pp);
        float4 n0 = n4[0], n1 = n4[1], n2 = n4[2];
        float4 i0 = i4[0], i1 = i4[1], i2 = i4[2];
        float4 f0 = f4[0], f1 = f4[1], f2 = f4[2];

        // gather 4 pixels into arrays (SoA in registers)
        float NX[4] = {n0.x, n0.w, n1.z, n2.y}, NY[4] = {n0.y, n1.x, n1.w, n2.z},
              NZ[4] = {n0.z, n1.y, n2.x, n2.w};
        float IX[4] = {i0.x, i0.w, i1.z, i2.y}, IY[4] = {i0.y, i1.x, i1.w, i2.z},
              IZ[4] = {i0.z, i1.y, i2.x, i2.w};
        float FX[4] = {f0.x, f0.w, f1.z, f2.y}, FY[4] = {f0.y, f1.x, f1.w, f2.z},
              FZ[4] = {f0.z, f1.y, f2.x, f2.w};
        float CM[4] = {c4.x, c4.y, c4.z, c4.w};

        // per-pixel: geometry + sigmoids, weights consumed immediately by
        // fire-and-forget LDS atomics (no lgkmcnt waits anywhere in this loop)
        #pragma unroll
        for (int p = 0; p < 4; ++p) {
            float dt = FX[p] * NX[p] + FY[p] * NY[p] + FZ[p] * NZ[p];
            dt = fminf(fmaxf(dt, 0.0f), 1.0f);
            float lx = IX[p] - 0.002f;
            float lxy2 = lx * lx + IY[p] * IY[p];
            float l2 = lxy2 + IZ[p] * IZ[p];
            float ld = __builtin_amdgcn_sqrtf(l2);
            float lm = __builtin_amdgcn_exp2f(
                lmask_c * lxy2 * __builtin_amdgcn_rcpf(IZ[p] * IZ[p]));
            float cm3 = CM[p] * CM[p] * CM[p];
            float r = dt * lm * kconst * cm3 * __builtin_amdgcn_rcpf(l2);
            float di = __builtin_amdgcn_sqrtf(
                IX[p] * IX[p] + IY[p] * IY[p] + IZ[p] * IZ[p]);
            float d = (di + ld) * half_inv_bin;     // depth in bin units

            int j0 = (int)floorf(d);
            j0 = j0 < 5 ? 5 : (j0 > 57 ? 57 : j0);
            const int k0 = j0 - 5;                  // centered window, in [0, 52]
            float e0 = __builtin_amdgcn_exp2f(((float)k0 - d) * THREE_LOG2E);
            float S[WIN + 1];
            #pragma unroll
            for (int m = 0; m < WIN + 1; ++m)       // independent fma+rcp
                S[m] = __builtin_amdgcn_rcpf(fmaf(e0, E3P[m], 1.0f));

            float* hp = hq + k0;
            #pragma unroll
            for (int m = 0; m < WIN; ++m)           // ds_add_f32, offset:4m folded
                atomicAdd(&hp[m], r * (S[m] - S[m + 1]));
        }
    }
    __syncthreads();

    // reduce 16 quarter-wave histograms -> 64-bin block partial
    if (tid < NBINS) {
        float s = 0.0f;
        #pragma unroll
        for (int h = 0; h < NHIST; ++h) s += hist[h * HSTRIDE + tid];
        ws[(size_t)blockIdx.x * NBINS + tid] = s;
    }
}

__global__ __launch_bounds__(256) void spad_reduce_kernel(
    const float* __restrict__ ws, float* __restrict__ out)
{
    const int o = blockIdx.x * 256 + threadIdx.x;  // 0..2047 -> (b, k)
    const int b = o >> 6;
    const int k = o & 63;
    float s = 0.0f;
    #pragma unroll
    for (int c = 0; c < SPLIT; ++c)
        s += ws[((size_t)(c * NBATCH + b)) * NBINS + k];
    out[o] = s;   // every element written -> no memset needed
}

extern "C" void kernel_launch(void* const* d_in, const int* in_sizes, int n_in,
                              void* d_out, int out_size, void* d_ws, size_t ws_size,
                              hipStream_t stream) {
    const float* normals = (const float*)d_in[0];
    const float* inters  = (const float*)d_in[1];
    const float* film    = (const float*)d_in[2];
    const float* cosm    = (const float*)d_in[3];
    float* out = (float*)d_out;
    float* ws  = (float*)d_ws;   // needs 1024*64*4 = 256 KiB

    // host-side double-precision constants (argument setup; capture-safe)
    const double fov_rad = 33.0 * M_PI / 180.0;
    const double width = 2.0 * tan(fov_rad / 2.0);
    const double kconst_d = width * width / M_PI / 65536.0;       // width^2/pi/R^2
    const double sig = tan(21.5 * M_PI / 180.0) / 1.4;
    const double log2e = 1.4426950408889634;
    const double lmask_c_d = -log2e / (2.0 * sig * sig);          // exp2 scale
    const double half_inv_bin_d = 0.5 / 0.0136;

    spad_hist_kernel<<<NBATCH * SPLIT, BLOCKT, 0, stream>>>(
        normals, inters, film, cosm, ws,
        (float)kconst_d, (float)lmask_c_d, (float)half_inv_bin_d);

    spad_reduce_kernel<<<(NBATCH * NBINS) / 256, 256, 0, stream>>>(ws, out);
}

// Round 2
// 106.679 us; speedup vs baseline: 1.9489x; 1.9489x over previous
//
#include <hip/hip_runtime.h>
#include <math.h>

// Problem constants
#define NPIX    65536      // 256*256 pixels per camera
#define NBINS   64
#define NBATCH  32         // B*C = 4*8
#define SPLIT   32         // pixel-chunks per batch
#define BLOCKT  256
#define PXPT    4          // pixels per thread per iteration
#define ITERS   (NPIX / SPLIT / (BLOCKT * PXPT))   // = 2 -> 8 px/thread
//
// R8 THEORY: R7's ds_add_f32 atomics serialized (depths cluster at ~bin 36 ->
// all 16 sharing lanes hit the same addresses; same-address LDS atomics are
// N-way serial). VALUBusy was 4%. Root fix: NO LDS in the hot loop at all.
// Full 64-bin histogram lives in VGPRs (statically indexed, fully unrolled).
// This removes the need for windowing: evaluate all 65 sigmoid edges with
// 2 exp2 + 65 independent v_rcp per pixel (table split at k=16/k=48 keeps
// e^{3(k-d)} products in f32 range; saturation to 0/1 on over/underflow is
// exactly the correct asymptote). ~220 VALU + 72 trans per pixel ->
// ~8us execution floor per CU, matching the ~8us HBM read floor (51 MB).
// Epilogue: 4 chunked LDS tree reductions (bins 16 at a time, stride 17).
// NOTE (R6, still applies): software prefetch of global loads REGRESSED;
// keep simple per-iteration loads.

#define THREE_LOG2E 4.328085122666891f

__global__ __launch_bounds__(BLOCKT, 3) void spad_hist_kernel(
    const float* __restrict__ normals,      // [32, 65536, 3]
    const float* __restrict__ inters,       // [32, 65536, 3]
    const float* __restrict__ film,         // [65536, 3]
    const float* __restrict__ cosm,         // [65536]
    float* __restrict__ ws,                 // [1024, 64] block partials
    float kconst, float lmask_c, float half_inv_bin)
{
    __shared__ float red[BLOCKT * 17];      // epilogue reduction scratch (17.4 KB)
    const int tid = threadIdx.x;

    const int b = blockIdx.x & (NBATCH - 1);
    const int chunk = blockIdx.x / NBATCH;
    const int pix0 = chunk * (NPIX / SPLIT);

    // e^{3*(i-16)} for i = 0..32  (spans e^-48 .. e^48, all normal f32)
    const float T33[33] = {
        1.4251640827409352e-21f, 2.8625185805493937e-20f, 5.7495222642929500e-19f,
        1.1548224173015786e-17f, 2.3195228302435696e-16f, 4.6588861451033980e-15f,
        9.3576229688401746e-14f, 1.8795288165390832e-12f, 3.7751345442790977e-11f,
        7.5825604279119066e-10f, 1.5229979744712628e-08f, 3.0590232050182579e-07f,
        6.1442123533282098e-06f, 1.2340980408667956e-04f, 2.4787521766663585e-03f,
        4.9787068367863944e-02f, 1.0f,
        20.085536923187668f, 403.42879349273511f, 8103.0839275753840f,
        162754.79141900392f, 3269017.3724721107f, 65659969.137330510f,
        1318815734.4832146f, 26489122129.843472f, 532048240601.79865f,
        10686474581524.462f, 214643579785916.06f, 4311231547115195.0f,
        8.6593400423993746e+16f, 1.7392749415205010e+18f, 3.4934271057485095e+19f,
        7.0167359120976313e+20f };

    // register-resident histogram — all indexing compile-time (rule #20)
    float W[NBINS];
    #pragma unroll
    for (int k = 0; k < NBINS; ++k) W[k] = 0.0f;

    #pragma unroll
    for (int it = 0; it < ITERS; ++it) {
        const int pp = pix0 + (it * BLOCKT + tid) * PXPT;
        const float4* n4 = (const float4*)(normals + ((size_t)b * NPIX + pp) * 3);
        const float4* i4 = (const float4*)(inters  + ((size_t)b * NPIX + pp) * 3);
        const float4* f4 = (const float4*)(film + (size_t)pp * 3);
        const float4  c4 = *(const float4*)(cosm + pp);
        float4 n0 = n4[0], n1 = n4[1], n2 = n4[2];
        float4 i0 = i4[0], i1 = i4[1], i2 = i4[2];
        float4 f0 = f4[0], f1 = f4[1], f2 = f4[2];

        // gather 4 pixels into arrays (SoA in registers)
        float NX[4] = {n0.x, n0.w, n1.z, n2.y}, NY[4] = {n0.y, n1.x, n1.w, n2.z},
              NZ[4] = {n0.z, n1.y, n2.x, n2.w};
        float IX[4] = {i0.x, i0.w, i1.z, i2.y}, IY[4] = {i0.y, i1.x, i1.w, i2.z},
              IZ[4] = {i0.z, i1.y, i2.x, i2.w};
        float FX[4] = {f0.x, f0.w, f1.z, f2.y}, FY[4] = {f0.y, f1.x, f1.w, f2.z},
              FZ[4] = {f0.z, f1.y, f2.x, f2.w};
        float CM[4] = {c4.x, c4.y, c4.z, c4.w};

        #pragma unroll
        for (int p = 0; p < 4; ++p) {
            float dt = FX[p] * NX[p] + FY[p] * NY[p] + FZ[p] * NZ[p];
            dt = fminf(fmaxf(dt, 0.0f), 1.0f);
            float lx = IX[p] - 0.002f;
            float lxy2 = lx * lx + IY[p] * IY[p];
            float l2 = lxy2 + IZ[p] * IZ[p];
            float ldst = __builtin_amdgcn_sqrtf(l2);
            float lm = __builtin_amdgcn_exp2f(
                lmask_c * lxy2 * __builtin_amdgcn_rcpf(IZ[p] * IZ[p]));
            float cm3 = CM[p] * CM[p] * CM[p];
            float r = dt * lm * kconst * cm3 * __builtin_amdgcn_rcpf(l2);
            float di = __builtin_amdgcn_sqrtf(
                IX[p] * IX[p] + IY[p] * IY[p] + IZ[p] * IZ[p]);
            float d = (di + ldst) * half_inv_bin;   // depth in bin units

            // two split origins keep e0*T33[] in f32 range for all k;
            // overflow -> S=0, underflow -> S=1: both are the true asymptote
            float e0a = __builtin_amdgcn_exp2f(
                fmaf(d, -THREE_LOG2E, 16.0f * THREE_LOG2E));
            float e0b = __builtin_amdgcn_exp2f(
                fmaf(d, -THREE_LOG2E, 48.0f * THREE_LOG2E));

            // rolling-edge accumulation: S_k independent rcps, only 2 live
            float sp = __builtin_amdgcn_rcpf(fmaf(e0a, T33[0], 1.0f)); // S_0
            #pragma unroll
            for (int k = 0; k < NBINS; ++k) {
                const float e0 = (k < 32) ? e0a : e0b;
                const float tm = (k < 32) ? T33[k + 1] : T33[k - 31];
                float sn = __builtin_amdgcn_rcpf(fmaf(e0, tm, 1.0f));  // S_{k+1}
                W[k] = fmaf(r, sp - sn, W[k]);
                sp = sn;
            }
        }
    }

    // epilogue: reduce 256 register histograms -> block partial, 16 bins/round
    #pragma unroll
    for (int c = 0; c < NBINS / 16; ++c) {
        __syncthreads();
        #pragma unroll
        for (int j = 0; j < 16; ++j) red[tid * 17 + j] = W[c * 16 + j];
        __syncthreads();
        const int g = tid >> 4, j = tid & 15;
        float s = 0.0f;
        #pragma unroll
        for (int i = 0; i < 16; ++i) s += red[(g * 16 + i) * 17 + j];
        __syncthreads();
        red[tid] = s;                        // partial(g, j) at g*16 + j == tid
        __syncthreads();
        if (tid < 16) {
            float rr = 0.0f;
            #pragma unroll
            for (int gg = 0; gg < 16; ++gg) rr += red[gg * 16 + tid];
            ws[(size_t)blockIdx.x * NBINS + c * 16 + tid] = rr;
        }
    }
}

__global__ __launch_bounds__(256) void spad_reduce_kernel(
    const float* __restrict__ ws, float* __restrict__ out)
{
    const int o = blockIdx.x * 256 + threadIdx.x;  // 0..2047 -> (b, k)
    const int b = o >> 6;
    const int k = o & 63;
    float s = 0.0f;
    #pragma unroll
    for (int c = 0; c < SPLIT; ++c)
        s += ws[((size_t)(c * NBATCH + b)) * NBINS + k];
    out[o] = s;   // every element written -> no memset needed
}

extern "C" void kernel_launch(void* const* d_in, const int* in_sizes, int n_in,
                              void* d_out, int out_size, void* d_ws, size_t ws_size,
                              hipStream_t stream) {
    const float* normals = (const float*)d_in[0];
    const float* inters  = (const float*)d_in[1];
    const float* film    = (const float*)d_in[2];
    const float* cosm    = (const float*)d_in[3];
    float* out = (float*)d_out;
    float* ws  = (float*)d_ws;   // needs 1024*64*4 = 256 KiB

    // host-side double-precision constants (argument setup; capture-safe)
    const double fov_rad = 33.0 * M_PI / 180.0;
    const double width = 2.0 * tan(fov_rad / 2.0);
    const double kconst_d = width * width / M_PI / 65536.0;       // width^2/pi/R^2
    const double sig = tan(21.5 * M_PI / 180.0) / 1.4;
    const double log2e = 1.4426950408889634;
    const double lmask_c_d = -log2e / (2.0 * sig * sig);          // exp2 scale
    const double half_inv_bin_d = 0.5 / 0.0136;

    spad_hist_kernel<<<NBATCH * SPLIT, BLOCKT, 0, stream>>>(
        normals, inters, film, cosm, ws,
        (float)kconst_d, (float)lmask_c_d, (float)half_inv_bin_d);

    spad_reduce_kernel<<<(NBATCH * NBINS) / 256, 256, 0, stream>>>(ws, out);
}

// Round 3
// 101.961 us; speedup vs baseline: 2.0390x; 1.0463x over previous
//
#include <hip/hip_runtime.h>
#include <math.h>

// Problem constants
#define NPIX    65536      // 256*256 pixels per camera
#define NBINS   64
#define NBATCH  32         // B*C = 4*8
#define SPLIT   32         // pixel-chunks per batch
#define BLOCKT  256
#define PXPT    4          // pixels per thread per iteration
#define ITERS   (NPIX / SPLIT / (BLOCKT * PXPT))   // = 2 -> 8 px/thread
//
// R8 (kept): NO LDS in the hot loop. Full histogram in VGPRs, static indexing.
// All 65 sigmoid edges via 2 exp2 + 65 independent v_rcp (table split at
// k=16/k=48 keeps e^{3(k-d)} in f32 range; over/underflow saturates to the
// mathematically-correct 0/1 asymptote).
// R9: (a) TELESCOPED accumulators: A[j] += r*s_j per edge (2 VALU + 1 trans,
// was 3+1); per-thread W[k] = A[k]-A[k+1] in the epilogue. Cancellation error
// ~ulp(A) ~ 2e-11/thread — far below threshold. (b) __launch_bounds__(256,4)
// pins VGPR <= 128: R8's W[64]+rolling-S+staging likely crossed 128 -> 2
// waves/SIMD (occupancy quantum halves at 64/128/256), leaving trans latency
// unhidden. Telescoping drops enough pressure to fit 128 (est. ~116).
// R7 lesson (kept): no LDS atomics in hot loop — clustered depths serialize.
// R6 lesson (kept): software prefetch of global loads regressed; simple loads.

#define THREE_LOG2E 4.328085122666891f

__global__ __launch_bounds__(BLOCKT, 4) void spad_hist_kernel(
    const float* __restrict__ normals,      // [32, 65536, 3]
    const float* __restrict__ inters,       // [32, 65536, 3]
    const float* __restrict__ film,         // [65536, 3]
    const float* __restrict__ cosm,         // [65536]
    float* __restrict__ ws,                 // [1024, 64] block partials
    float kconst, float lmask_c, float half_inv_bin)
{
    __shared__ float red[BLOCKT * 17];      // epilogue reduction scratch (17.4 KB)
    const int tid = threadIdx.x;

    const int b = blockIdx.x & (NBATCH - 1);
    const int chunk = blockIdx.x / NBATCH;
    const int pix0 = chunk * (NPIX / SPLIT);

    // e^{3*(i-16)} for i = 0..32  (spans e^-48 .. e^48, all normal f32)
    const float T33[33] = {
        1.4251640827409352e-21f, 2.8625185805493937e-20f, 5.7495222642929500e-19f,
        1.1548224173015786e-17f, 2.3195228302435696e-16f, 4.6588861451033980e-15f,
        9.3576229688401746e-14f, 1.8795288165390832e-12f, 3.7751345442790977e-11f,
        7.5825604279119066e-10f, 1.5229979744712628e-08f, 3.0590232050182579e-07f,
        6.1442123533282098e-06f, 1.2340980408667956e-04f, 2.4787521766663585e-03f,
        4.9787068367863944e-02f, 1.0f,
        20.085536923187668f, 403.42879349273511f, 8103.0839275753840f,
        162754.79141900392f, 3269017.3724721107f, 65659969.137330510f,
        1318815734.4832146f, 26489122129.843472f, 532048240601.79865f,
        10686474581524.462f, 214643579785916.06f, 4311231547115195.0f,
        8.6593400423993746e+16f, 1.7392749415205010e+18f, 3.4934271057485095e+19f,
        7.0167359120976313e+20f };

    // register-resident EDGE accumulators A[j] = sum(r * sigmoid(3(d-j)))
    // — all indexing compile-time (rule #20)
    float A[NBINS + 1];
    #pragma unroll
    for (int j = 0; j <= NBINS; ++j) A[j] = 0.0f;

    #pragma unroll
    for (int it = 0; it < ITERS; ++it) {
        const int pp = pix0 + (it * BLOCKT + tid) * PXPT;
        const float4* n4 = (const float4*)(normals + ((size_t)b * NPIX + pp) * 3);
        const float4* i4 = (const float4*)(inters  + ((size_t)b * NPIX + pp) * 3);
        const float4* f4 = (const float4*)(film + (size_t)pp * 3);
        const float4  c4 = *(const float4*)(cosm + pp);
        float4 n0 = n4[0], n1 = n4[1], n2 = n4[2];
        float4 i0 = i4[0], i1 = i4[1], i2 = i4[2];
        float4 f0 = f4[0], f1 = f4[1], f2 = f4[2];

        // gather 4 pixels into arrays (SoA in registers)
        float NX[4] = {n0.x, n0.w, n1.z, n2.y}, NY[4] = {n0.y, n1.x, n1.w, n2.z},
              NZ[4] = {n0.z, n1.y, n2.x, n2.w};
        float IX[4] = {i0.x, i0.w, i1.z, i2.y}, IY[4] = {i0.y, i1.x, i1.w, i2.z},
              IZ[4] = {i0.z, i1.y, i2.x, i2.w};
        float FX[4] = {f0.x, f0.w, f1.z, f2.y}, FY[4] = {f0.y, f1.x, f1.w, f2.z},
              FZ[4] = {f0.z, f1.y, f2.x, f2.w};
        float CM[4] = {c4.x, c4.y, c4.z, c4.w};

        #pragma unroll
        for (int p = 0; p < 4; ++p) {
            float dt = FX[p] * NX[p] + FY[p] * NY[p] + FZ[p] * NZ[p];
            dt = fminf(fmaxf(dt, 0.0f), 1.0f);
            float lx = IX[p] - 0.002f;
            float lxy2 = lx * lx + IY[p] * IY[p];
            float l2 = lxy2 + IZ[p] * IZ[p];
            float ldst = __builtin_amdgcn_sqrtf(l2);
            float lm = __builtin_amdgcn_exp2f(
                lmask_c * lxy2 * __builtin_amdgcn_rcpf(IZ[p] * IZ[p]));
            float cm3 = CM[p] * CM[p] * CM[p];
            float r = dt * lm * kconst * cm3 * __builtin_amdgcn_rcpf(l2);
            float di = __builtin_amdgcn_sqrtf(
                IX[p] * IX[p] + IY[p] * IY[p] + IZ[p] * IZ[p]);
            float d = (di + ldst) * half_inv_bin;   // depth in bin units

            // two split origins keep e0*T33[] in f32 range for all j;
            // overflow -> s=0, underflow -> s=1: both are the true asymptote
            float e0a = __builtin_amdgcn_exp2f(
                fmaf(d, -THREE_LOG2E, 16.0f * THREE_LOG2E));
            float e0b = __builtin_amdgcn_exp2f(
                fmaf(d, -THREE_LOG2E, 48.0f * THREE_LOG2E));

            // edges 0..32: u = e0a * e^{3(j-16)};  edges 33..64: e0b * e^{3(j-48)}
            // 2 VALU + 1 trans per edge, 65 fully-independent chains
            #pragma unroll
            for (int j = 0; j <= 32; ++j)
                A[j] = fmaf(r,
                    __builtin_amdgcn_rcpf(fmaf(e0a, T33[j], 1.0f)), A[j]);
            #pragma unroll
            for (int j = 33; j <= 64; ++j)
                A[j] = fmaf(r,
                    __builtin_amdgcn_rcpf(fmaf(e0b, T33[j - 32], 1.0f)), A[j]);
        }
    }

    // epilogue: per-thread W[k] = A[k] - A[k+1], then reduce 256 histograms
    // -> block partial, 16 bins per round
    #pragma unroll
    for (int c = 0; c < NBINS / 16; ++c) {
        __syncthreads();
        #pragma unroll
        for (int j = 0; j < 16; ++j)
            red[tid * 17 + j] = A[c * 16 + j] - A[c * 16 + j + 1];
        __syncthreads();
        const int g = tid >> 4, j = tid & 15;
        float s = 0.0f;
        #pragma unroll
        for (int i = 0; i < 16; ++i) s += red[(g * 16 + i) * 17 + j];
        __syncthreads();
        red[tid] = s;                        // partial(g, j) at g*16 + j == tid
        __syncthreads();
        if (tid < 16) {
            float rr = 0.0f;
            #pragma unroll
            for (int gg = 0; gg < 16; ++gg) rr += red[gg * 16 + tid];
            ws[(size_t)blockIdx.x * NBINS + c * 16 + tid] = rr;
        }
    }
}

__global__ __launch_bounds__(256) void spad_reduce_kernel(
    const float* __restrict__ ws, float* __restrict__ out)
{
    const int o = blockIdx.x * 256 + threadIdx.x;  // 0..2047 -> (b, k)
    const int b = o >> 6;
    const int k = o & 63;
    float s = 0.0f;
    #pragma unroll
    for (int c = 0; c < SPLIT; ++c)
        s += ws[((size_t)(c * NBATCH + b)) * NBINS + k];
    out[o] = s;   // every element written -> no memset needed
}

extern "C" void kernel_launch(void* const* d_in, const int* in_sizes, int n_in,
                              void* d_out, int out_size, void* d_ws, size_t ws_size,
                              hipStream_t stream) {
    const float* normals = (const float*)d_in[0];
    const float* inters  = (const float*)d_in[1];
    const float* film    = (const float*)d_in[2];
    const float* cosm    = (const float*)d_in[3];
    float* out = (float*)d_out;
    float* ws  = (float*)d_ws;   // needs 1024*64*4 = 256 KiB

    // host-side double-precision constants (argument setup; capture-safe)
    const double fov_rad = 33.0 * M_PI / 180.0;
    const double width = 2.0 * tan(fov_rad / 2.0);
    const double kconst_d = width * width / M_PI / 65536.0;       // width^2/pi/R^2
    const double sig = tan(21.5 * M_PI / 180.0) / 1.4;
    const double log2e = 1.4426950408889634;
    const double lmask_c_d = -log2e / (2.0 * sig * sig);          // exp2 scale
    const double half_inv_bin_d = 0.5 / 0.0136;

    spad_hist_kernel<<<NBATCH * SPLIT, BLOCKT, 0, stream>>>(
        normals, inters, film, cosm, ws,
        (float)kconst_d, (float)lmask_c_d, (float)half_inv_bin_d);

    spad_reduce_kernel<<<(NBATCH * NBINS) / 256, 256, 0, stream>>>(ws, out);
}